// Round 1
// baseline (443.375 us; speedup 1.0000x reference)
//
#include <hip/hip_runtime.h>

// MeshVerticalLayer: out[c,b,j] = cc_mul(x[:,b,lperm[r]], diag[:,r])
//                               + cc_mul(x[:,b,lperm[p]], off[:,p]),  r=rperm[j], p=pair[r]
// x: [2,B,N] fp32, N=1024, B=32768. HBM-bound: 256MB in + 256MB out.

#define NCOLS 1024
#define TPB   256
#define KPT   (NCOLS / TPB)   // 4 columns per thread
#define BPB   8               // batches per block

__global__ __launch_bounds__(TPB) void mesh_kernel(
    const float* __restrict__ x,      // [2,B,N]
    const float* __restrict__ diag,   // [2,N]
    const float* __restrict__ offd,   // [2,N]
    const int*   __restrict__ pair,   // [N]
    const int*   __restrict__ lperm,  // [N]
    const int*   __restrict__ rperm,  // [N]
    float* __restrict__ out,          // [2,B,N]
    int B)
{
    // double-buffered staging: [buf][channel0 row | channel1 row]
    __shared__ __align__(16) float smem[2][2 * NCOLS];

    const int t = threadIdx.x;

    // Per-column index/coefficient table (same for all batches) -> registers
    int   lr[KPT], lp[KPT];
    float d0[KPT], d1[KPT], f0[KPT], f1[KPT];
#pragma unroll
    for (int k = 0; k < KPT; ++k) {
        int j = t + k * TPB;
        int r = rperm[j];
        int p = pair[r];            // = r ^ 1
        lr[k] = lperm[r];
        lp[k] = lperm[p];
        d0[k] = diag[r];
        d1[k] = diag[NCOLS + r];
        f0[k] = offd[p];
        f1[k] = offd[NCOLS + p];
    }

    const long long BN = (long long)B * NCOLS;
    const int b0 = blockIdx.x * BPB;

    for (int i = 0; i < BPB; ++i) {
        int b = b0 + i;
        if (b >= B) break;
        float* sb = smem[i & 1];

        // stage both channel rows, coalesced float4 (256 thr * 16B = 4KB/row)
        const float4* r0 = (const float4*)(x + (long long)b * NCOLS);
        const float4* r1 = (const float4*)(x + BN + (long long)b * NCOLS);
        ((float4*)sb)[t]           = r0[t];
        ((float4*)(sb + NCOLS))[t] = r1[t];
        __syncthreads();   // writes to buf(i&1) visible; prior-iter reads of this
                           // buffer were drained at the previous barrier

#pragma unroll
        for (int k = 0; k < KPT; ++k) {
            float a0 = sb[lr[k]];
            float a1 = sb[NCOLS + lr[k]];
            float e0 = sb[lp[k]];
            float e1 = sb[NCOLS + lp[k]];
            int j = t + k * TPB;
            long long o = (long long)b * NCOLS + j;
            out[o]      = a0 * d0[k] - a1 * d1[k] + e0 * f0[k] - e1 * f1[k];
            out[BN + o] = a0 * d1[k] + a1 * d0[k] + e0 * f1[k] + e1 * f0[k];
        }
        // no second sync: double buffer + next iteration's barrier covers WAR
    }
}

extern "C" void kernel_launch(void* const* d_in, const int* in_sizes, int n_in,
                              void* d_out, int out_size, void* d_ws, size_t ws_size,
                              hipStream_t stream) {
    const float* x     = (const float*)d_in[0];
    const float* diag  = (const float*)d_in[1];
    const float* offd  = (const float*)d_in[2];
    const int*   pair  = (const int*)d_in[3];
    const int*   lperm = (const int*)d_in[4];
    const int*   rperm = (const int*)d_in[5];
    float* out = (float*)d_out;

    const int N = in_sizes[1] / 2;          // 1024
    const int B = in_sizes[0] / (2 * N);    // 32768
    (void)N;

    dim3 grid((B + BPB - 1) / BPB);         // 4096 blocks
    mesh_kernel<<<grid, TPB, 0, stream>>>(x, diag, offd, pair, lperm, rperm, out, B);
}